// Round 14
// baseline (355.256 us; speedup 1.0000x reference)
//
#include <hip/hip_runtime.h>

#define N_    8192
#define FIN_  256
#define NHID_ 128
#define E_    524288
#define KTOP  32
#define CAP   160    // bucket capacity per row; Binomial(E,1/N): mean 64, sigma 8 -> 160 = +12 sigma
#define HASHSZ 512   // LDS hash slots (unique cols <= CAP -> load factor <= 31%)

typedef unsigned short ushort_t;

// ---- fused: edge scatter + h = relu(x @ W1 + b1) + a,b epilogue ----
// 256 blocks (1/CU), 32 rows/block, thread = 4 rows x 4 cols -> per-CU W1 L1 traffic
// halves vs R13 (1 MB vs 2 MB; L1 is 64 B/cyc — the k_fused bottleneck).
__global__ __launch_bounds__(256) void k_fused(const float* __restrict__ x,
                                               const int* __restrict__ ei,
                                               const float* __restrict__ W1,
                                               const float* __restrict__ b1,
                                               const float* __restrict__ We,
                                               float* __restrict__ h,
                                               float* __restrict__ a,
                                               float* __restrict__ b,
                                               int* __restrict__ cnt,
                                               ushort_t* __restrict__ ecol) {
    __shared__ float xs[32][FIN_];   // 32 KB
    int t = threadIdx.x;
    int blk = blockIdx.x;

    // ---- scatter slice: 2048 edges, int4-coalesced (cnt pre-zeroed by memset) ----
#pragma unroll
    for (int u = 0; u < 2; ++u) {
        int e4 = blk * 512 + u * 256 + t;
        int4 r4 = ((const int4*)ei)[e4];
        int4 c4 = ((const int4*)(ei + E_))[e4];
        int p;
        p = atomicAdd(&cnt[r4.x], 1); if (p < CAP) ecol[r4.x * CAP + p] = (ushort_t)c4.x;
        p = atomicAdd(&cnt[r4.y], 1); if (p < CAP) ecol[r4.y * CAP + p] = (ushort_t)c4.y;
        p = atomicAdd(&cnt[r4.z], 1); if (p < CAP) ecol[r4.z * CAP + p] = (ushort_t)c4.z;
        p = atomicAdd(&cnt[r4.w], 1); if (p < CAP) ecol[r4.w * CAP + p] = (ushort_t)c4.w;
    }

    // ---- stage 32 rows of x into LDS: 2048 float4, 8 per thread ----
    int row0 = blk * 32;
    const float4* xg = (const float4*)(x + (size_t)row0 * FIN_);
    float4* xs4 = (float4*)&xs[0][0];
#pragma unroll
    for (int i = 0; i < 8; ++i) xs4[t + 256 * i] = xg[t + 256 * i];
    __syncthreads();

    int rg = t >> 5;           // 8 row-groups x 4 rows = 32 rows
    int jg = t & 31;           // col-group: cols 4*jg .. 4*jg+3
    int rb = rg * 4;
    const float* wp = W1 + jg * 4;
    float4 bb = *(const float4*)(b1 + jg * 4);
    float4 acc0 = bb, acc1 = bb, acc2 = bb, acc3 = bb;
    const float* xr0 = xs[rb + 0];
    const float* xr1 = xs[rb + 1];
    const float* xr2 = xs[rb + 2];
    const float* xr3 = xs[rb + 3];
#pragma unroll 4
    for (int k = 0; k < FIN_; ++k) {
        float4 w = *(const float4*)(wp + (size_t)k * NHID_);
        float x0 = xr0[k], x1 = xr1[k], x2 = xr2[k], x3 = xr3[k];
        acc0.x = fmaf(x0, w.x, acc0.x); acc0.y = fmaf(x0, w.y, acc0.y);
        acc0.z = fmaf(x0, w.z, acc0.z); acc0.w = fmaf(x0, w.w, acc0.w);
        acc1.x = fmaf(x1, w.x, acc1.x); acc1.y = fmaf(x1, w.y, acc1.y);
        acc1.z = fmaf(x1, w.z, acc1.z); acc1.w = fmaf(x1, w.w, acc1.w);
        acc2.x = fmaf(x2, w.x, acc2.x); acc2.y = fmaf(x2, w.y, acc2.y);
        acc2.z = fmaf(x2, w.z, acc2.z); acc2.w = fmaf(x2, w.w, acc2.w);
        acc3.x = fmaf(x3, w.x, acc3.x); acc3.y = fmaf(x3, w.y, acc3.y);
        acc3.z = fmaf(x3, w.z, acc3.z); acc3.w = fmaf(x3, w.w, acc3.w);
    }
    acc0.x = fmaxf(acc0.x, 0.f); acc0.y = fmaxf(acc0.y, 0.f);
    acc0.z = fmaxf(acc0.z, 0.f); acc0.w = fmaxf(acc0.w, 0.f);
    acc1.x = fmaxf(acc1.x, 0.f); acc1.y = fmaxf(acc1.y, 0.f);
    acc1.z = fmaxf(acc1.z, 0.f); acc1.w = fmaxf(acc1.w, 0.f);
    acc2.x = fmaxf(acc2.x, 0.f); acc2.y = fmaxf(acc2.y, 0.f);
    acc2.z = fmaxf(acc2.z, 0.f); acc2.w = fmaxf(acc2.w, 0.f);
    acc3.x = fmaxf(acc3.x, 0.f); acc3.y = fmaxf(acc3.y, 0.f);
    acc3.z = fmaxf(acc3.z, 0.f); acc3.w = fmaxf(acc3.w, 0.f);
    *(float4*)(h + (size_t)(row0 + rb + 0) * NHID_ + jg * 4) = acc0;
    *(float4*)(h + (size_t)(row0 + rb + 1) * NHID_ + jg * 4) = acc1;
    *(float4*)(h + (size_t)(row0 + rb + 2) * NHID_ + jg * 4) = acc2;
    *(float4*)(h + (size_t)(row0 + rb + 3) * NHID_ + jg * 4) = acc3;

    // ---- epilogue: a,b per-node scalars (32-lane tree per row) ----
    float4 we1 = *(const float4*)(We + jg * 4);
    float4 we2 = *(const float4*)(We + NHID_ + jg * 4);
    float p0 = acc0.x * we1.x + acc0.y * we1.y + acc0.z * we1.z + acc0.w * we1.w;
    float p1 = acc1.x * we1.x + acc1.y * we1.y + acc1.z * we1.z + acc1.w * we1.w;
    float p2 = acc2.x * we1.x + acc2.y * we1.y + acc2.z * we1.z + acc2.w * we1.w;
    float p3 = acc3.x * we1.x + acc3.y * we1.y + acc3.z * we1.z + acc3.w * we1.w;
    float q0 = acc0.x * we2.x + acc0.y * we2.y + acc0.z * we2.z + acc0.w * we2.w;
    float q1 = acc1.x * we2.x + acc1.y * we2.y + acc1.z * we2.z + acc1.w * we2.w;
    float q2 = acc2.x * we2.x + acc2.y * we2.y + acc2.z * we2.z + acc2.w * we2.w;
    float q3 = acc3.x * we2.x + acc3.y * we2.y + acc3.z * we2.z + acc3.w * we2.w;
#pragma unroll
    for (int o = 16; o > 0; o >>= 1) {
        p0 += __shfl_down(p0, o, 32); q0 += __shfl_down(q0, o, 32);
        p1 += __shfl_down(p1, o, 32); q1 += __shfl_down(q1, o, 32);
        p2 += __shfl_down(p2, o, 32); q2 += __shfl_down(q2, o, 32);
        p3 += __shfl_down(p3, o, 32); q3 += __shfl_down(q3, o, 32);
    }
    if (jg == 0) {
        a[row0 + rb + 0] = p0; b[row0 + rb + 0] = q0;
        a[row0 + rb + 1] = p1; b[row0 + rb + 1] = q1;
        a[row0 + rb + 2] = p2; b[row0 + rb + 2] = q2;
        a[row0 + rb + 3] = p3; b[row0 + rb + 3] = q3;
    }
}

// ---- per-row sparsemax + topK (R13, unchanged): hash dup-detect + LDS rank +
//      wave-0 shuffle tau/thresh + single streaming write pass ----
__global__ __launch_bounds__(256) void k_rows(const int* __restrict__ cnt,
                                              const ushort_t* __restrict__ ecol,
                                              const float* __restrict__ a,
                                              const float* __restrict__ b,
                                              const float* __restrict__ be,
                                              float* __restrict__ adj) {
    __shared__ float zs[CAP];
    __shared__ int   cols[CAP];
    __shared__ float srt[CAP];
    __shared__ unsigned char dupf[CAP];
    __shared__ unsigned char dupsrt[CAP];
    __shared__ unsigned int bitmap[N_ / 32];
    __shared__ int   hcol[HASHSZ];
    __shared__ int   hidx[HASHSZ];
    __shared__ float hval[HASHSZ];
    __shared__ float s_tau, s_thresh;

    int r = blockIdx.x;
    int t = threadIdx.x;
    int m = cnt[r];
    if (m > CAP) m = CAP;

    bitmap[t] = 0u;
    hcol[t] = -1;         hcol[t + 256] = -1;
    hidx[t] = 0x7fffffff; hidx[t + 256] = 0x7fffffff;
    float ab = a[r] + be[0];
    for (int i = t; i < m; i += 256) {
        int c = (int)ecol[r * CAP + i];
        cols[i] = c;
        zs[i] = ab + b[c];
    }
    __syncthreads();

    if (m > 0) {
        for (int i = t; i < m; i += 256) {
            int c = cols[i];
            int slot = c & (HASHSZ - 1);
            while (true) {
                int old = atomicCAS(&hcol[slot], -1, c);
                if (old == -1 || old == c) { atomicMin(&hidx[slot], i); break; }
                slot = (slot + 1) & (HASHSZ - 1);
            }
        }
        __syncthreads();

        for (int i = t; i < m; i += 256) {
            float zi = zs[i];
            int ci = cols[i];
            int rank = 0;
            for (int jj = 0; jj < m; ++jj) {
                float zj = zs[jj];
                rank += (zj > zi) || (zj == zi && jj < i);
            }
            int slot = ci & (HASHSZ - 1);
            while (hcol[slot] != ci) slot = (slot + 1) & (HASHSZ - 1);
            bool dup = (hidx[slot] != i);
            srt[rank] = zi;
            dupsrt[rank] = dup ? 1 : 0;
            dupf[i] = dup ? 1 : 0;
        }
        __syncthreads();

        if (t < 64) {
            int lane = t;
            float v0 = (lane       < m) ? srt[lane]       : 0.f;
            float v1 = (lane + 64  < m) ? srt[lane + 64]  : 0.f;
            float v2 = (lane + 128 < m) ? srt[lane + 128] : 0.f;
            bool  d0 = (lane       < m) ? (dupsrt[lane]       != 0) : false;
            bool  d1 = (lane + 64  < m) ? (dupsrt[lane + 64]  != 0) : false;
            bool  d2 = (lane + 128 < m) ? (dupsrt[lane + 128] != 0) : false;

            float sc0 = v0, sc1 = v1, sc2 = v2;
#pragma unroll
            for (int o = 1; o < 64; o <<= 1) {
                float u0 = __shfl_up(sc0, o);
                float u1 = __shfl_up(sc1, o);
                float u2 = __shfl_up(sc2, o);
                if (lane >= o) { sc0 += u0; sc1 += u1; sc2 += u2; }
            }
            float tot0 = __shfl(sc0, 63);
            sc1 += tot0;
            float tot1 = __shfl(sc1, 63);
            sc2 += tot1;

            bool k0 = (lane       < m) && (1.f + (float)(lane + 1)   * v0 > sc0);
            bool k1 = (lane + 64  < m) && (1.f + (float)(lane + 65)  * v1 > sc1);
            bool k2 = (lane + 128 < m) && (1.f + (float)(lane + 129) * v2 > sc2);
            unsigned long long kb0 = __ballot(k0), kb1 = __ballot(k1), kb2 = __ballot(k2);
            int kmax;
            if (kb2)      kmax = 128 + 63 - (int)__builtin_clzll(kb2) + 1;
            else if (kb1) kmax = 64  + 63 - (int)__builtin_clzll(kb1) + 1;
            else          kmax =       63 - (int)__builtin_clzll(kb0) + 1;
            int ki = kmax - 1, ks = ki >> 6, kl = ki & 63;
            float csk = (ks == 0) ? __shfl(sc0, kl) : (ks == 1) ? __shfl(sc1, kl) : __shfl(sc2, kl);
            float tau = (csk - 1.f) / (float)kmax;

            unsigned long long dm0 = __ballot(d0), dm1 = __ballot(d1), dm2 = __ballot(d2);
            unsigned long long below = (1ull << lane) - 1ull;
            int pc0 = (int)__popcll(dm0 & below);
            int pc1 = (int)__popcll(dm0) + (int)__popcll(dm1 & below);
            int pc2 = (int)__popcll(dm0) + (int)__popcll(dm1) + (int)__popcll(dm2 & below);
            float cand = 0.f;
            if (lane       < m && !d0 && (lane       - pc0) == KTOP - 1) cand = fmaxf(cand, fmaxf(v0 - tau, 0.f));
            if (lane + 64  < m && !d1 && (lane + 64  - pc1) == KTOP - 1) cand = fmaxf(cand, fmaxf(v1 - tau, 0.f));
            if (lane + 128 < m && !d2 && (lane + 128 - pc2) == KTOP - 1) cand = fmaxf(cand, fmaxf(v2 - tau, 0.f));
#pragma unroll
            for (int o = 32; o > 0; o >>= 1) cand = fmaxf(cand, __shfl_down(cand, o));
            if (lane == 0) { s_tau = tau; s_thresh = cand; }
        }
        __syncthreads();
        float tau = s_tau;
        float thresh = s_thresh;

        for (int i = t; i < m; i += 256) {
            if (dupf[i]) continue;
            float s = zs[i] - tau;
            if (s > 0.f && s >= thresh) {
                int c = cols[i];
                atomicOr(&bitmap[c >> 5], 1u << (c & 31));
                int slot = c & (HASHSZ - 1);
                while (hcol[slot] != c) slot = (slot + 1) & (HASHSZ - 1);
                hval[slot] = s;
            }
        }
    }
    __syncthreads();

    float4* row4 = (float4*)(adj + (size_t)r * N_);
#pragma unroll
    for (int k2 = 0; k2 < 8; ++k2) {
        int idx = t + 256 * k2;
        unsigned int word = bitmap[idx >> 3];
        unsigned int nib = (word >> ((idx & 7) * 4)) & 0xFu;
        float4 v = make_float4(0.f, 0.f, 0.f, 0.f);
        if (nib) {
            int cbase = idx * 4;
#pragma unroll
            for (int bbit = 0; bbit < 4; ++bbit) {
                if (nib & (1u << bbit)) {
                    int c = cbase + bbit;
                    int slot = c & (HASHSZ - 1);
                    while (hcol[slot] != c) slot = (slot + 1) & (HASHSZ - 1);
                    float val = hval[slot];
                    if (bbit == 0) v.x = val;
                    else if (bbit == 1) v.y = val;
                    else if (bbit == 2) v.z = val;
                    else v.w = val;
                }
            }
        }
        row4[idx] = v;
    }
}

extern "C" void kernel_launch(void* const* d_in, const int* in_sizes, int n_in,
                              void* d_out, int out_size, void* d_ws, size_t ws_size,
                              hipStream_t stream) {
    const float* x  = (const float*)d_in[0];
    const int*   ei = (const int*)d_in[1];
    const float* W1 = (const float*)d_in[2];
    const float* b1 = (const float*)d_in[3];
    const float* We = (const float*)d_in[4];
    const float* be = (const float*)d_in[5];

    float* h_out   = (float*)d_out;                 // (N, NHID)
    float* adj_out = h_out + (size_t)N_ * NHID_;    // (N, N)

    float*    a    = (float*)d_ws;                  // N f32
    float*    b    = a + N_;                        // N f32
    int*      cnt  = (int*)(b + N_);                // N i32
    ushort_t* ecol = (ushort_t*)(cnt + N_);         // N*CAP u16

    (void)hipMemsetAsync(cnt, 0, N_ * sizeof(int), stream);
    k_fused<<<256, 256, 0, stream>>>(x, ei, W1, b1, We, h_out, a, b, cnt, ecol);
    k_rows <<<N_, 256, 0, stream>>>(cnt, ecol, a, b, be, adj_out);
}

// Round 15
// 334.466 us; speedup vs baseline: 1.0622x; 1.0622x over previous
//
#include <hip/hip_runtime.h>

#define N_    8192
#define FIN_  256
#define NHID_ 128
#define E_    524288
#define KTOP  32
#define CAP   160    // bucket capacity per row; Binomial(E,1/N): mean 64, sigma 8 -> 160 = +12 sigma
#define HASHSZ 512   // LDS hash slots (unique cols <= CAP -> load factor <= 31%)

typedef unsigned short ushort_t;

// ---- fused: edge scatter + h = relu(x @ W1 + b1) + a,b epilogue ----
// 512 blocks (2/CU): 16 rows/block, thread = 2 rows x 4 cols. 2 waves/SIMD hides
// L1 latency on the 8x-redundant W1 reads (R14's 1 block/CU regressed: 1 wave/SIMD
// exposes L1 latency + scatter imbalance).
__global__ __launch_bounds__(256) void k_fused(const float* __restrict__ x,
                                               const int* __restrict__ ei,
                                               const float* __restrict__ W1,
                                               const float* __restrict__ b1,
                                               const float* __restrict__ We,
                                               float* __restrict__ h,
                                               float* __restrict__ a,
                                               float* __restrict__ b,
                                               int* __restrict__ cnt,
                                               ushort_t* __restrict__ ecol) {
    __shared__ float xs[16][FIN_];
    int t = threadIdx.x;
    int blk = blockIdx.x;

    {
        int4 r4 = ((const int4*)ei)[blk * 256 + t];
        int4 c4 = ((const int4*)(ei + E_))[blk * 256 + t];
        int p;
        p = atomicAdd(&cnt[r4.x], 1); if (p < CAP) ecol[r4.x * CAP + p] = (ushort_t)c4.x;
        p = atomicAdd(&cnt[r4.y], 1); if (p < CAP) ecol[r4.y * CAP + p] = (ushort_t)c4.y;
        p = atomicAdd(&cnt[r4.z], 1); if (p < CAP) ecol[r4.z * CAP + p] = (ushort_t)c4.z;
        p = atomicAdd(&cnt[r4.w], 1); if (p < CAP) ecol[r4.w * CAP + p] = (ushort_t)c4.w;
    }

    int row0 = blk * 16;
    const float4* xg = (const float4*)(x + (size_t)row0 * FIN_);
    float4* xs4 = (float4*)&xs[0][0];
#pragma unroll
    for (int i = 0; i < 4; ++i) xs4[t + 256 * i] = xg[t + 256 * i];
    __syncthreads();

    int rg = t >> 5;
    int jg = t & 31;
    int r0 = 2 * rg, r1 = 2 * rg + 1;
    const float* wp = W1 + jg * 4;
    float4 bb = *(const float4*)(b1 + jg * 4);
    float4 acc0 = bb, acc1 = bb;
    const float* xr0 = xs[r0];
    const float* xr1 = xs[r1];
#pragma unroll 8
    for (int k = 0; k < FIN_; ++k) {
        float4 w = *(const float4*)(wp + (size_t)k * NHID_);
        float x0 = xr0[k], x1 = xr1[k];
        acc0.x = fmaf(x0, w.x, acc0.x);
        acc0.y = fmaf(x0, w.y, acc0.y);
        acc0.z = fmaf(x0, w.z, acc0.z);
        acc0.w = fmaf(x0, w.w, acc0.w);
        acc1.x = fmaf(x1, w.x, acc1.x);
        acc1.y = fmaf(x1, w.y, acc1.y);
        acc1.z = fmaf(x1, w.z, acc1.z);
        acc1.w = fmaf(x1, w.w, acc1.w);
    }
    acc0.x = fmaxf(acc0.x, 0.f); acc0.y = fmaxf(acc0.y, 0.f);
    acc0.z = fmaxf(acc0.z, 0.f); acc0.w = fmaxf(acc0.w, 0.f);
    acc1.x = fmaxf(acc1.x, 0.f); acc1.y = fmaxf(acc1.y, 0.f);
    acc1.z = fmaxf(acc1.z, 0.f); acc1.w = fmaxf(acc1.w, 0.f);
    *(float4*)(h + (size_t)(row0 + r0) * NHID_ + jg * 4) = acc0;
    *(float4*)(h + (size_t)(row0 + r1) * NHID_ + jg * 4) = acc1;

    float4 we1 = *(const float4*)(We + jg * 4);
    float4 we2 = *(const float4*)(We + NHID_ + jg * 4);
    float p0 = acc0.x * we1.x + acc0.y * we1.y + acc0.z * we1.z + acc0.w * we1.w;
    float q0 = acc0.x * we2.x + acc0.y * we2.y + acc0.z * we2.z + acc0.w * we2.w;
    float p1 = acc1.x * we1.x + acc1.y * we1.y + acc1.z * we1.z + acc1.w * we1.w;
    float q1 = acc1.x * we2.x + acc1.y * we2.y + acc1.z * we2.z + acc1.w * we2.w;
#pragma unroll
    for (int o = 16; o > 0; o >>= 1) {
        p0 += __shfl_down(p0, o, 32);
        q0 += __shfl_down(q0, o, 32);
        p1 += __shfl_down(p1, o, 32);
        q1 += __shfl_down(q1, o, 32);
    }
    if (jg == 0) {
        a[row0 + r0] = p0; b[row0 + r0] = q0;
        a[row0 + r1] = p1; b[row0 + r1] = q1;
    }
}

// ---- per-row sparsemax + topK (R13): hash dup-detect + LDS rank + wave-0 shuffle
//      tau/thresh + single streaming write pass ----
__global__ __launch_bounds__(256) void k_rows(const int* __restrict__ cnt,
                                              const ushort_t* __restrict__ ecol,
                                              const float* __restrict__ a,
                                              const float* __restrict__ b,
                                              const float* __restrict__ be,
                                              float* __restrict__ adj) {
    __shared__ float zs[CAP];
    __shared__ int   cols[CAP];
    __shared__ float srt[CAP];
    __shared__ unsigned char dupf[CAP];
    __shared__ unsigned char dupsrt[CAP];
    __shared__ unsigned int bitmap[N_ / 32];
    __shared__ int   hcol[HASHSZ];
    __shared__ int   hidx[HASHSZ];
    __shared__ float hval[HASHSZ];
    __shared__ float s_tau, s_thresh;

    int r = blockIdx.x;
    int t = threadIdx.x;
    int m = cnt[r];
    if (m > CAP) m = CAP;

    bitmap[t] = 0u;
    hcol[t] = -1;         hcol[t + 256] = -1;
    hidx[t] = 0x7fffffff; hidx[t + 256] = 0x7fffffff;
    float ab = a[r] + be[0];
    for (int i = t; i < m; i += 256) {
        int c = (int)ecol[r * CAP + i];
        cols[i] = c;
        zs[i] = ab + b[c];
    }
    __syncthreads();

    if (m > 0) {
        for (int i = t; i < m; i += 256) {
            int c = cols[i];
            int slot = c & (HASHSZ - 1);
            while (true) {
                int old = atomicCAS(&hcol[slot], -1, c);
                if (old == -1 || old == c) { atomicMin(&hidx[slot], i); break; }
                slot = (slot + 1) & (HASHSZ - 1);
            }
        }
        __syncthreads();

        for (int i = t; i < m; i += 256) {
            float zi = zs[i];
            int ci = cols[i];
            int rank = 0;
            for (int jj = 0; jj < m; ++jj) {
                float zj = zs[jj];
                rank += (zj > zi) || (zj == zi && jj < i);
            }
            int slot = ci & (HASHSZ - 1);
            while (hcol[slot] != ci) slot = (slot + 1) & (HASHSZ - 1);
            bool dup = (hidx[slot] != i);
            srt[rank] = zi;
            dupsrt[rank] = dup ? 1 : 0;
            dupf[i] = dup ? 1 : 0;
        }
        __syncthreads();

        if (t < 64) {
            int lane = t;
            float v0 = (lane       < m) ? srt[lane]       : 0.f;
            float v1 = (lane + 64  < m) ? srt[lane + 64]  : 0.f;
            float v2 = (lane + 128 < m) ? srt[lane + 128] : 0.f;
            bool  d0 = (lane       < m) ? (dupsrt[lane]       != 0) : false;
            bool  d1 = (lane + 64  < m) ? (dupsrt[lane + 64]  != 0) : false;
            bool  d2 = (lane + 128 < m) ? (dupsrt[lane + 128] != 0) : false;

            float sc0 = v0, sc1 = v1, sc2 = v2;
#pragma unroll
            for (int o = 1; o < 64; o <<= 1) {
                float u0 = __shfl_up(sc0, o);
                float u1 = __shfl_up(sc1, o);
                float u2 = __shfl_up(sc2, o);
                if (lane >= o) { sc0 += u0; sc1 += u1; sc2 += u2; }
            }
            float tot0 = __shfl(sc0, 63);
            sc1 += tot0;
            float tot1 = __shfl(sc1, 63);
            sc2 += tot1;

            bool k0 = (lane       < m) && (1.f + (float)(lane + 1)   * v0 > sc0);
            bool k1 = (lane + 64  < m) && (1.f + (float)(lane + 65)  * v1 > sc1);
            bool k2 = (lane + 128 < m) && (1.f + (float)(lane + 129) * v2 > sc2);
            unsigned long long kb0 = __ballot(k0), kb1 = __ballot(k1), kb2 = __ballot(k2);
            int kmax;
            if (kb2)      kmax = 128 + 63 - (int)__builtin_clzll(kb2) + 1;
            else if (kb1) kmax = 64  + 63 - (int)__builtin_clzll(kb1) + 1;
            else          kmax =       63 - (int)__builtin_clzll(kb0) + 1;
            int ki = kmax - 1, ks = ki >> 6, kl = ki & 63;
            float csk = (ks == 0) ? __shfl(sc0, kl) : (ks == 1) ? __shfl(sc1, kl) : __shfl(sc2, kl);
            float tau = (csk - 1.f) / (float)kmax;

            unsigned long long dm0 = __ballot(d0), dm1 = __ballot(d1), dm2 = __ballot(d2);
            unsigned long long below = (1ull << lane) - 1ull;
            int pc0 = (int)__popcll(dm0 & below);
            int pc1 = (int)__popcll(dm0) + (int)__popcll(dm1 & below);
            int pc2 = (int)__popcll(dm0) + (int)__popcll(dm1) + (int)__popcll(dm2 & below);
            float cand = 0.f;
            if (lane       < m && !d0 && (lane       - pc0) == KTOP - 1) cand = fmaxf(cand, fmaxf(v0 - tau, 0.f));
            if (lane + 64  < m && !d1 && (lane + 64  - pc1) == KTOP - 1) cand = fmaxf(cand, fmaxf(v1 - tau, 0.f));
            if (lane + 128 < m && !d2 && (lane + 128 - pc2) == KTOP - 1) cand = fmaxf(cand, fmaxf(v2 - tau, 0.f));
#pragma unroll
            for (int o = 32; o > 0; o >>= 1) cand = fmaxf(cand, __shfl_down(cand, o));
            if (lane == 0) { s_tau = tau; s_thresh = cand; }
        }
        __syncthreads();
        float tau = s_tau;
        float thresh = s_thresh;

        for (int i = t; i < m; i += 256) {
            if (dupf[i]) continue;
            float s = zs[i] - tau;
            if (s > 0.f && s >= thresh) {
                int c = cols[i];
                atomicOr(&bitmap[c >> 5], 1u << (c & 31));
                int slot = c & (HASHSZ - 1);
                while (hcol[slot] != c) slot = (slot + 1) & (HASHSZ - 1);
                hval[slot] = s;
            }
        }
    }
    __syncthreads();

    float4* row4 = (float4*)(adj + (size_t)r * N_);
#pragma unroll
    for (int k2 = 0; k2 < 8; ++k2) {
        int idx = t + 256 * k2;
        unsigned int word = bitmap[idx >> 3];
        unsigned int nib = (word >> ((idx & 7) * 4)) & 0xFu;
        float4 v = make_float4(0.f, 0.f, 0.f, 0.f);
        if (nib) {
            int cbase = idx * 4;
#pragma unroll
            for (int bbit = 0; bbit < 4; ++bbit) {
                if (nib & (1u << bbit)) {
                    int c = cbase + bbit;
                    int slot = c & (HASHSZ - 1);
                    while (hcol[slot] != c) slot = (slot + 1) & (HASHSZ - 1);
                    float val = hval[slot];
                    if (bbit == 0) v.x = val;
                    else if (bbit == 1) v.y = val;
                    else if (bbit == 2) v.z = val;
                    else v.w = val;
                }
            }
        }
        row4[idx] = v;
    }
}

extern "C" void kernel_launch(void* const* d_in, const int* in_sizes, int n_in,
                              void* d_out, int out_size, void* d_ws, size_t ws_size,
                              hipStream_t stream) {
    const float* x  = (const float*)d_in[0];
    const int*   ei = (const int*)d_in[1];
    const float* W1 = (const float*)d_in[2];
    const float* b1 = (const float*)d_in[3];
    const float* We = (const float*)d_in[4];
    const float* be = (const float*)d_in[5];

    float* h_out   = (float*)d_out;                 // (N, NHID)
    float* adj_out = h_out + (size_t)N_ * NHID_;    // (N, N)

    float*    a    = (float*)d_ws;                  // N f32
    float*    b    = a + N_;                        // N f32
    int*      cnt  = (int*)(b + N_);                // N i32
    ushort_t* ecol = (ushort_t*)(cnt + N_);         // N*CAP u16

    (void)hipMemsetAsync(cnt, 0, N_ * sizeof(int), stream);
    k_fused<<<512, 256, 0, stream>>>(x, ei, W1, b1, We, h_out, a, b, cnt, ecol);
    k_rows <<<N_, 256, 0, stream>>>(cnt, ecol, a, b, be, adj_out);
}